// Round 3
// baseline (197.899 us; speedup 1.0000x reference)
//
#include <hip/hip_runtime.h>
#include <stdint.h>

#define DD 128                 // drug feature dim
#define HH 32                  // hidden dim
#define RS 36                  // f16 per h-row (72 B): 18m mod 32 distinct -> <=2-way (free)
#define TABQ (4096 * DD / 4)   // float4 count of drug table
#define BLOB_OFF (1u << 20)    // weight fragment blob offset inside d_ws (bytes)

typedef _Float16 f16;
typedef _Float16 f16x4 __attribute__((ext_vector_type(4)));
typedef _Float16 f16x8 __attribute__((ext_vector_type(8)));
typedef float    f32x4 __attribute__((ext_vector_type(4)));

// Pre-pass: (a) drug table f32->f16 (blocks 0..511); (b) weight-fragment blob
// at ws+1MB (block 512): W1 slots 0..511, W2 512..639, W3 640..767,
// W4-column-fragment 768..831 (lane m==0 holds W4[8q+j], else 0).
__global__ __launch_bounds__(256)
void synergy_prepass(const float* __restrict__ drug,
                     const float* __restrict__ W1, const float* __restrict__ W2,
                     const float* __restrict__ W3, const float* __restrict__ W4,
                     f16* __restrict__ tab)
{
    const int tid = threadIdx.x;
    if ((int)blockIdx.x == 512) {
        f16x8* __restrict__ blob16 = (f16x8*)((char*)tab + BLOB_OFF);
        const float4* __restrict__ W1v = (const float4*)W1;
        #pragma unroll
        for (int p = 0; p < 2; ++p) {
            const int S = p * 256 + tid;
            const int t = S >> 8, f = (S >> 6) & 3, l = S & 63;
            const int mm = l & 15, qq = l >> 4;
            const int c4 = (t * 16 + mm) * (DD / 4) + f * 8 + qq * 2;
            const float4 w0 = W1v[c4], w1 = W1v[c4 + 1];
            f16x8 r;
            r[0]=(f16)w0.x; r[1]=(f16)w0.y; r[2]=(f16)w0.z; r[3]=(f16)w0.w;
            r[4]=(f16)w1.x; r[5]=(f16)w1.y; r[6]=(f16)w1.z; r[7]=(f16)w1.w;
            blob16[S] = r;
        }
        {
            const int B = tid & 127;
            const int t = B >> 6, l = B & 63;
            const int mm = l & 15, qq = l >> 4;
            const int c4 = (t * 16 + mm) * (HH / 4) + qq * 2;
            const float4* __restrict__ src = (tid < 128) ? (const float4*)W2 : (const float4*)W3;
            const float4 w0 = src[c4], w1 = src[c4 + 1];
            f16x8 r;
            r[0]=(f16)w0.x; r[1]=(f16)w0.y; r[2]=(f16)w0.z; r[3]=(f16)w0.w;
            r[4]=(f16)w1.x; r[5]=(f16)w1.y; r[6]=(f16)w1.z; r[7]=(f16)w1.w;
            blob16[512 + (tid & 128) + B] = r;
        }
        if (tid < 64) {                         // W4 column fragment
            const int mm = tid & 15, qq = tid >> 4;
            f16x8 r;
            #pragma unroll
            for (int j = 0; j < 8; ++j)
                r[j] = (mm == 0) ? (f16)W4[qq * 8 + j] : (f16)0.0f;
            blob16[768 + tid] = r;
        }
        return;
    }
    const int i = blockIdx.x * 256 + tid;
    if (i < TABQ) {
        const float4 v = ((const float4*)drug)[i];
        f16x4 h;
        h[0]=(f16)v.x; h[1]=(f16)v.y; h[2]=(f16)v.z; h[3]=(f16)v.w;
        ((f16x4*)tab)[i] = h;
    }
}

// Main v4: v3 with the occupancy cap released. v3's counters showed the
// kernel latency-bound with everything idle (MfmaUtil 4.6%, VALUBusy 20%,
// occupancy 33%) and NEITHER resource limiting: VGPR=60 (<=64), LDS=17.9KB
// (8x17.9=143KB <= 160KB). The 4-blocks/CU launch bound itself was the
// limiter. 8 waves/SIMD doubles the latency-hiding pool for the same serial
// per-wave chain (gather-wait -> A -> 3x hbuf LDS round-trips -> D).
// VGPR budget for 8 waves/SIMD is 64; v3 used 60 naturally, so no spill
// expected (verify via WRITE_SIZE staying at 3.9 MB).
__global__ __launch_bounds__(256, 8)
void synergy_main(const f16* __restrict__ tab, const int* __restrict__ edges,
                  const float* __restrict__ b1, const float* __restrict__ b2,
                  const float* __restrict__ b3, const float* __restrict__ b4,
                  float* __restrict__ out, int E, int NG)
{
    __shared__ __align__(16) f16x8 wlds[832];      // 13 KiB: W1|W2|W3|W4 fragments
    __shared__ __align__(16) f16 hbuf[4][16 * RS]; // 4.5 KiB per block

    const int tid  = threadIdx.x;
    const int wave = tid >> 6;
    const int lane = tid & 63;
    const int m    = lane & 15;
    const int q    = lane >> 4;

    const char* __restrict__ tabB   = (const char*)tab;
    const f16x8* __restrict__ blobG = (const f16x8*)(tabB + BLOB_OFF);

    // block-cooperative weight-fragment copy into LDS (once)
    wlds[tid]       = blobG[tid];
    wlds[256 + tid] = blobG[256 + tid];
    wlds[512 + tid] = blobG[512 + tid];
    if (tid < 64) wlds[768 + tid] = blobG[768 + tid];
    __syncthreads();

    const int WSTR = (int)gridDim.x * 4;
    int g = (int)blockIdx.x * 4 + wave;
    if (g >= NG) return;

    const int4* __restrict__ edges4 = (const int4*)edges;

    const float b1a = b1[m], b1b = b1[16 + m];
    const float b2a = b2[m], b2b = b2[16 + m];
    const float b3a = b3[m], b3b = b3[16 + m];
    const float b4v = b4[0];

    f16* __restrict__ hb = hbuf[wave];

    auto load_ed = [&](int gg) -> int4 {
        int e = (gg << 4) + m;
        e = (e < E) ? e : (E - 1);
        return edges4[e];
    };

    // Gather registers: v[f][t] holds edge-m's halfs [32f+8q, +8) of table t.
    f16x8 v[4][3];
    auto issue_gather = [&](const int4 ed) {
        const char* __restrict__ p0 = tabB + ((ed.x << 8) | (q << 4));
        const char* __restrict__ p1 = tabB + ((ed.y << 8) | (q << 4));
        const char* __restrict__ p2 = tabB + ((ed.z << 8) | (q << 4));
        #pragma unroll
        for (int f = 0; f < 4; ++f) {
            v[f][0] = *(const f16x8*)(p0 + f * 64);
            v[f][1] = *(const f16x8*)(p1 + f * 64);
            v[f][2] = *(const f16x8*)(p2 + f * 64);
        }
    };

    // ---- prologue: gathers for group g in flight
    int4 ed_cur = load_ed(g);
    issue_gather(ed_cur);
    int gn = g + WSTR;
    int4 ed_nxt = load_ed((gn < NG) ? gn : g);

    int wzero = 0;                       // opaque 0: pins weight reads in LDS
    for (;;) {
        asm volatile("" : "+v"(wzero)); // redefined every iter -> no LICM hoist
        const f16x8* __restrict__ wl = wlds + wzero;

        // ---- Phase A: L1 (8 MFMAs, K=128); consumes v[] (counted vmcnt waits)
        f32x4 acc0 = {b1a, b1a, b1a, b1a};
        f32x4 acc1 = {b1b, b1b, b1b, b1b};
        #pragma unroll
        for (int f = 0; f < 4; ++f) {
            const f16x8 wa0 = wl[f * 64 + lane];
            const f16x8 wa1 = wl[256 + f * 64 + lane];
            const f16x8 p = v[f][0] * v[f][1] * v[f][2];
            acc0 = __builtin_amdgcn_mfma_f32_16x16x32_f16(p, wa0, acc0, 0, 0, 0);
            acc1 = __builtin_amdgcn_mfma_f32_16x16x32_f16(p, wa1, acc1, 0, 0, 0);
        }
        #pragma unroll
        for (int r = 0; r < 4; ++r) {
            const int row = 4 * q + r;
            hb[row * RS + m]      = (f16)fmaxf(acc0[r], 0.0f);
            hb[row * RS + 16 + m] = (f16)fmaxf(acc1[r], 0.0f);
        }

        // ---- refill: issue next group's 12 gathers NOW; flight covered by B-D
        const bool last = (gn >= NG);
        int4 ed_fut = ed_nxt;
        if (!last) {
            issue_gather(ed_nxt);
            const int gf = gn + WSTR;
            ed_fut = load_ed((gf < NG) ? gf : g);
        }

        // ---- Phase B: L2
        {
            const f16x8 a2 = *(const f16x8*)(hb + m * RS + q * 8);
            f32x4 c0 = {b2a, b2a, b2a, b2a};
            f32x4 c1 = {b2b, b2b, b2b, b2b};
            c0 = __builtin_amdgcn_mfma_f32_16x16x32_f16(a2, wl[512 + lane], c0, 0, 0, 0);
            c1 = __builtin_amdgcn_mfma_f32_16x16x32_f16(a2, wl[576 + lane], c1, 0, 0, 0);
            #pragma unroll
            for (int r = 0; r < 4; ++r) {
                const int row = 4 * q + r;
                hb[row * RS + m]      = (f16)fmaxf(c0[r], 0.0f);
                hb[row * RS + 16 + m] = (f16)fmaxf(c1[r], 0.0f);
            }
        }

        // ---- Phase C: L3 (h3 back to LDS for L4's A-operand)
        {
            const f16x8 a3 = *(const f16x8*)(hb + m * RS + q * 8);
            f32x4 d0 = {b3a, b3a, b3a, b3a};
            f32x4 d1 = {b3b, b3b, b3b, b3b};
            d0 = __builtin_amdgcn_mfma_f32_16x16x32_f16(a3, wl[640 + lane], d0, 0, 0, 0);
            d1 = __builtin_amdgcn_mfma_f32_16x16x32_f16(a3, wl[704 + lane], d1, 0, 0, 0);
            #pragma unroll
            for (int r = 0; r < 4; ++r) {
                const int row = 4 * q + r;
                hb[row * RS + m]      = (f16)fmaxf(d0[r], 0.0f);
                hb[row * RS + 16 + m] = (f16)fmaxf(d1[r], 0.0f);
            }
        }

        // ---- Phase D: L4 as MFMA vs zero-padded W4 column; col 0 = result
        {
            const f16x8 a4 = *(const f16x8*)(hb + m * RS + q * 8);
            f32x4 z = {b4v, b4v, b4v, b4v};
            z = __builtin_amdgcn_mfma_f32_16x16x32_f16(a4, wl[768 + lane], z, 0, 0, 0);
            if (m == 0) {                        // lanes 0,16,32,48: rows 4q..4q+3
                const int e0 = (g << 4) + 4 * q;
                float4 res;
                res.x = 1.0f / (1.0f + __expf(-z[0]));
                res.y = 1.0f / (1.0f + __expf(-z[1]));
                res.z = 1.0f / (1.0f + __expf(-z[2]));
                res.w = 1.0f / (1.0f + __expf(-z[3]));
                if (e0 + 3 < E) *(float4*)(out + e0) = res;
                else {
                    if (e0 + 0 < E) out[e0 + 0] = res.x;
                    if (e0 + 1 < E) out[e0 + 1] = res.y;
                    if (e0 + 2 < E) out[e0 + 2] = res.z;
                }
            }
        }
        // label pass-through
        const int eL = (g << 4) + lane;
        if (lane < 16 && eL < E) out[E + eL] = (float)ed_cur.w;

        if (last) break;
        g = gn; gn += WSTR; ed_cur = ed_nxt; ed_nxt = ed_fut;
    }
}

extern "C" void kernel_launch(void* const* d_in, const int* in_sizes, int n_in,
                              void* d_out, int out_size, void* d_ws, size_t ws_size,
                              hipStream_t stream)
{
    const float* drug  = (const float*)d_in[0];
    // d_in[1] (cell_hidden_out), d_in[3] (proj_W), d_in[4] (proj_b): dead code
    const int*   edges = (const int*)d_in[2];
    const float* W1 = (const float*)d_in[5];
    const float* b1 = (const float*)d_in[6];
    const float* W2 = (const float*)d_in[7];
    const float* b2 = (const float*)d_in[8];
    const float* W3 = (const float*)d_in[9];
    const float* b3 = (const float*)d_in[10];
    const float* W4 = (const float*)d_in[11];
    const float* b4 = (const float*)d_in[12];
    float* out = (float*)d_out;
    f16*   tab = (f16*)d_ws;   // [0,1MB): f16 table; [1MB,+13KB): weight blob

    const int E  = in_sizes[2] / 4;
    const int NG = (E + 15) / 16;

    hipLaunchKernelGGL(synergy_prepass, dim3(513), dim3(256), 0, stream,
                       drug, W1, W2, W3, W4, tab);
    int blocks = (NG + 3) / 4;
    if (blocks > 2048) blocks = 2048;        // 8 blocks/CU x 256 CUs
    hipLaunchKernelGGL(synergy_main, dim3(blocks), dim3(256), 0, stream,
                       tab, edges, b1, b2, b3, b4, out, E, NG);
}

// Round 4
// 132.470 us; speedup vs baseline: 1.4939x; 1.4939x over previous
//
#include <hip/hip_runtime.h>
#include <stdint.h>

#define DD 128                 // drug feature dim
#define HH 32                  // hidden dim
#define TABQ (4096 * DD / 4)   // float4 count of drug table
#define BLOB_OFF (1u << 20)    // weight fragment blob offset inside d_ws (bytes)

typedef _Float16 f16;
typedef _Float16 f16x2 __attribute__((ext_vector_type(2)));
typedef _Float16 f16x4 __attribute__((ext_vector_type(4)));
typedef _Float16 f16x8 __attribute__((ext_vector_type(8)));
typedef float    f32x4 __attribute__((ext_vector_type(4)));
typedef uint32_t u32x4 __attribute__((ext_vector_type(4)));

// Pre-pass: (a) drug table f32->f16 (blocks 0..511); (b) weight-fragment blob
// at ws+1MB (block 512): W1 slots 0..511, W2 512..639, W3 640..767,
// W4-column-fragment 768..831 (lane m==0 holds W4[8q+j], else 0).
// NOTE: fragment contents are IDENTICAL for A- and B-operand roles (the
// 16x16x32 A/B lane mappings are symmetric), so v5's operand swap needs no
// blob change.
__global__ __launch_bounds__(256)
void synergy_prepass(const float* __restrict__ drug,
                     const float* __restrict__ W1, const float* __restrict__ W2,
                     const float* __restrict__ W3, const float* __restrict__ W4,
                     f16* __restrict__ tab)
{
    const int tid = threadIdx.x;
    if ((int)blockIdx.x == 512) {
        f16x8* __restrict__ blob16 = (f16x8*)((char*)tab + BLOB_OFF);
        const float4* __restrict__ W1v = (const float4*)W1;
        #pragma unroll
        for (int p = 0; p < 2; ++p) {
            const int S = p * 256 + tid;
            const int t = S >> 8, f = (S >> 6) & 3, l = S & 63;
            const int mm = l & 15, qq = l >> 4;
            const int c4 = (t * 16 + mm) * (DD / 4) + f * 8 + qq * 2;
            const float4 w0 = W1v[c4], w1 = W1v[c4 + 1];
            f16x8 r;
            r[0]=(f16)w0.x; r[1]=(f16)w0.y; r[2]=(f16)w0.z; r[3]=(f16)w0.w;
            r[4]=(f16)w1.x; r[5]=(f16)w1.y; r[6]=(f16)w1.z; r[7]=(f16)w1.w;
            blob16[S] = r;
        }
        {
            const int B = tid & 127;
            const int t = B >> 6, l = B & 63;
            const int mm = l & 15, qq = l >> 4;
            const int c4 = (t * 16 + mm) * (HH / 4) + qq * 2;
            const float4* __restrict__ src = (tid < 128) ? (const float4*)W2 : (const float4*)W3;
            const float4 w0 = src[c4], w1 = src[c4 + 1];
            f16x8 r;
            r[0]=(f16)w0.x; r[1]=(f16)w0.y; r[2]=(f16)w0.z; r[3]=(f16)w0.w;
            r[4]=(f16)w1.x; r[5]=(f16)w1.y; r[6]=(f16)w1.z; r[7]=(f16)w1.w;
            blob16[512 + (tid & 128) + B] = r;
        }
        if (tid < 64) {                         // W4 column fragment
            const int mm = tid & 15, qq = tid >> 4;
            f16x8 r;
            #pragma unroll
            for (int j = 0; j < 8; ++j)
                r[j] = (mm == 0) ? (f16)W4[qq * 8 + j] : (f16)0.0f;
            blob16[768 + tid] = r;
        }
        return;
    }
    const int i = blockIdx.x * 256 + tid;
    if (i < TABQ) {
        const float4 v = ((const float4*)drug)[i];
        f16x4 h;
        h[0]=(f16)v.x; h[1]=(f16)v.y; h[2]=(f16)v.z; h[3]=(f16)v.w;
        ((f16x4*)tab)[i] = h;
    }
}

// pack two f32 -> one dword of 2 f16 (same RNE rounding as scalar casts)
static __device__ __forceinline__ uint32_t pkh(float a, float b) {
    f16x2 h; h[0] = (f16)a; h[1] = (f16)b;
    return __builtin_bit_cast(uint32_t, h);
}
static __device__ __forceinline__ void plswap32(uint32_t &a, uint32_t &b) {
#if __has_builtin(__builtin_amdgcn_permlane32_swap)
    auto r = __builtin_amdgcn_permlane32_swap(a, b, false, false);
    a = r[0]; b = r[1];
#else
    asm volatile("v_permlane32_swap_b32 %0, %1" : "+v"(a), "+v"(b));
#endif
}
static __device__ __forceinline__ void plswap16(uint32_t &a, uint32_t &b) {
#if __has_builtin(__builtin_amdgcn_permlane16_swap)
    auto r = __builtin_amdgcn_permlane16_swap(a, b, false, false);
    a = r[0]; b = r[1];
#else
    asm volatile("v_permlane16_swap_b32 %0, %1" : "+v"(a), "+v"(b));
#endif
}

// Inter-layer transition, all in-register (replaces an LDS write+read round
// trip). Input: swapped-MFMA output, lane (m,q): a0[r]=h[m][4q+r],
// a1[r]=h[m][16+4q+r]. Output: next-layer B-fragment, lane (m,q) holds
// h[m][8q..8q+7] after relu.
// Algebra: u0,u1 = packed cols(4q,4q+1),(4q+2,4q+3); v0,v1 = +16 versions.
//   P32(u,v):  a'=[u_q0,u_q1,v_q0,v_q1]  b'=[u_q2,u_q3,v_q2,v_q3]
//   P16(a',b'): x=[a'_q0,b'_q0,a'_q2,b'_q2] y=[a'_q1,b'_q1,a'_q3,b'_q3]
// => lane (m,q) ends with {x0,x1,y0,y1} = cols 8q..8q+7 of row m.
static __device__ __forceinline__ f16x8 transition(f32x4 a0, f32x4 a1) {
    uint32_t u0 = pkh(fmaxf(a0[0], 0.f), fmaxf(a0[1], 0.f));
    uint32_t u1 = pkh(fmaxf(a0[2], 0.f), fmaxf(a0[3], 0.f));
    uint32_t v0 = pkh(fmaxf(a1[0], 0.f), fmaxf(a1[1], 0.f));
    uint32_t v1 = pkh(fmaxf(a1[2], 0.f), fmaxf(a1[3], 0.f));
    plswap32(u0, v0);
    plswap32(u1, v1);
    plswap16(u0, v0);
    plswap16(u1, v1);
    u32x4 d; d[0] = u0; d[1] = u1; d[2] = v0; d[3] = v1;
    return __builtin_bit_cast(f16x8, d);
}

// Main v5: swapped-operand MFMA chain (A=weight frag, B=activation frag) so
// every layer's output is row-local to its lane; the 3 hbuf LDS round trips
// of v3 become pure-register permlane transitions. hbuf deleted. Biases are
// indexed by output-dim (4q+r) now, so they live in a 384B LDS blob and are
// re-read per iteration through the wzero pin (broadcast ds_read_b128, no
// VGPR cost, no LICM re-hoist). Weights stay in 13KB LDS (v3's pin). With
// the chain shortened, occupancy lifts one safe notch: 5 waves/SIMD (VGPR
// cap ~100 vs ~60 measured in v3; v4 proved 8/SIMD=64 spills).
__global__ __launch_bounds__(256, 5)
void synergy_main(const f16* __restrict__ tab, const int* __restrict__ edges,
                  const float* __restrict__ b1, const float* __restrict__ b2,
                  const float* __restrict__ b3, const float* __restrict__ b4,
                  float* __restrict__ out, int E, int NG)
{
    __shared__ __align__(16) f16x8 wlds[832];   // 13 KiB: W1|W2|W3|W4 fragments
    __shared__ __align__(16) float blds[96];    // b1|b2|b3 (32 floats each)

    const int tid  = threadIdx.x;
    const int wave = tid >> 6;
    const int lane = tid & 63;
    const int m    = lane & 15;
    const int q    = lane >> 4;

    const char* __restrict__ tabB   = (const char*)tab;
    const f16x8* __restrict__ blobG = (const f16x8*)(tabB + BLOB_OFF);

    // block-cooperative LDS init (once)
    wlds[tid]       = blobG[tid];
    wlds[256 + tid] = blobG[256 + tid];
    wlds[512 + tid] = blobG[512 + tid];
    if (tid < 64) wlds[768 + tid] = blobG[768 + tid];
    if (tid < 96) {
        const float* __restrict__ src = (tid < 32) ? b1 : ((tid < 64) ? b2 : b3);
        blds[tid] = src[tid & 31];
    }
    __syncthreads();

    const int WSTR = (int)gridDim.x * 4;
    int g = (int)blockIdx.x * 4 + wave;
    if (g >= NG) return;

    const int4* __restrict__ edges4 = (const int4*)edges;
    const float b4v = b4[0];

    auto load_ed = [&](int gg) -> int4 {
        int e = (gg << 4) + m;
        e = (e < E) ? e : (E - 1);
        return edges4[e];
    };

    // Gather registers: v[f][t] holds edge-m's halfs [32f+8q, +8) of table t.
    f16x8 v[4][3];
    auto issue_gather = [&](const int4 ed) {
        const char* __restrict__ p0 = tabB + ((ed.x << 8) | (q << 4));
        const char* __restrict__ p1 = tabB + ((ed.y << 8) | (q << 4));
        const char* __restrict__ p2 = tabB + ((ed.z << 8) | (q << 4));
        #pragma unroll
        for (int f = 0; f < 4; ++f) {
            v[f][0] = *(const f16x8*)(p0 + f * 64);
            v[f][1] = *(const f16x8*)(p1 + f * 64);
            v[f][2] = *(const f16x8*)(p2 + f * 64);
        }
    };

    // ---- prologue: gathers for group g in flight
    int4 ed_cur = load_ed(g);
    issue_gather(ed_cur);
    int gn = g + WSTR;
    int4 ed_nxt = load_ed((gn < NG) ? gn : g);

    int wzero = 0;                       // opaque 0: pins LDS reads in LDS
    for (;;) {
        asm volatile("" : "+v"(wzero)); // redefined every iter -> no LICM hoist
        const f16x8* __restrict__ wl = wlds + wzero;
        const f32x4* __restrict__ bl = (const f32x4*)blds + wzero;

        // ---- Phase A: L1 (8 MFMAs, K=128, swapped: D = W1.h^T)
        f32x4 acc0 = bl[q];             // b1[4q..4q+3]
        f32x4 acc1 = bl[4 + q];         // b1[16+4q..]
        #pragma unroll
        for (int f = 0; f < 4; ++f) {
            const f16x8 wa0 = wl[f * 64 + lane];
            const f16x8 wa1 = wl[256 + f * 64 + lane];
            const f16x8 p = v[f][0] * v[f][1] * v[f][2];
            acc0 = __builtin_amdgcn_mfma_f32_16x16x32_f16(wa0, p, acc0, 0, 0, 0);
            acc1 = __builtin_amdgcn_mfma_f32_16x16x32_f16(wa1, p, acc1, 0, 0, 0);
        }
        const f16x8 h1 = transition(acc0, acc1);

        // ---- refill: issue next group's 12 gathers NOW; flight covered by B-D
        const bool last = (gn >= NG);
        int4 ed_fut = ed_nxt;
        if (!last) {
            issue_gather(ed_nxt);
            const int gf = gn + WSTR;
            ed_fut = load_ed((gf < NG) ? gf : g);
        }

        // ---- Phase B: L2
        f32x4 c0 = bl[8 + q];
        f32x4 c1 = bl[12 + q];
        c0 = __builtin_amdgcn_mfma_f32_16x16x32_f16(wl[512 + lane], h1, c0, 0, 0, 0);
        c1 = __builtin_amdgcn_mfma_f32_16x16x32_f16(wl[576 + lane], h1, c1, 0, 0, 0);
        const f16x8 h2 = transition(c0, c1);

        // ---- Phase C: L3
        f32x4 d0 = bl[16 + q];
        f32x4 d1 = bl[20 + q];
        d0 = __builtin_amdgcn_mfma_f32_16x16x32_f16(wl[640 + lane], h2, d0, 0, 0, 0);
        d1 = __builtin_amdgcn_mfma_f32_16x16x32_f16(wl[704 + lane], h2, d1, 0, 0, 0);
        const f16x8 h3 = transition(d0, d1);

        // ---- Phase D: L4 vs zero-padded W4 row; lanes q==0 hold z[m] in reg0
        {
            f32x4 z = {b4v, b4v, b4v, b4v};
            z = __builtin_amdgcn_mfma_f32_16x16x32_f16(wl[768 + lane], h3, z, 0, 0, 0);
            if (q == 0) {
                const int e0 = (g << 4) + m;
                if (e0 < E) out[e0] = 1.0f / (1.0f + __expf(-z[0]));
            }
        }
        // label pass-through
        const int eL = (g << 4) + lane;
        if (lane < 16 && eL < E) out[E + eL] = (float)ed_cur.w;

        if (last) break;
        g = gn; gn += WSTR; ed_cur = ed_nxt; ed_nxt = ed_fut;
    }
}

extern "C" void kernel_launch(void* const* d_in, const int* in_sizes, int n_in,
                              void* d_out, int out_size, void* d_ws, size_t ws_size,
                              hipStream_t stream)
{
    const float* drug  = (const float*)d_in[0];
    // d_in[1] (cell_hidden_out), d_in[3] (proj_W), d_in[4] (proj_b): dead code
    const int*   edges = (const int*)d_in[2];
    const float* W1 = (const float*)d_in[5];
    const float* b1 = (const float*)d_in[6];
    const float* W2 = (const float*)d_in[7];
    const float* b2 = (const float*)d_in[8];
    const float* W3 = (const float*)d_in[9];
    const float* b3 = (const float*)d_in[10];
    const float* W4 = (const float*)d_in[11];
    const float* b4 = (const float*)d_in[12];
    float* out = (float*)d_out;
    f16*   tab = (f16*)d_ws;   // [0,1MB): f16 table; [1MB,+13KB): weight blob

    const int E  = in_sizes[2] / 4;
    const int NG = (E + 15) / 16;

    hipLaunchKernelGGL(synergy_prepass, dim3(513), dim3(256), 0, stream,
                       drug, W1, W2, W3, W4, tab);
    int blocks = (NG + 3) / 4;
    if (blocks > 1280) blocks = 1280;        // 5 blocks/CU x 256 CUs
    hipLaunchKernelGGL(synergy_main, dim3(blocks), dim3(256), 0, stream,
                       tab, edges, b1, b2, b3, b4, out, E, NG);
}